// Round 1
// baseline (2069.263 us; speedup 1.0000x reference)
//
#include <hip/hip_runtime.h>
#include <hip/hip_bf16.h>
#include <math.h>

// ---------------- small kernels ----------------

__global__ void init_deg_k(float* deg, int N) {
    int i = blockIdx.x * blockDim.x + threadIdx.x;
    if (i < N) deg[i] = 1.0f;   // self-loop weight
}

__global__ void deg_edges_k(const int* __restrict__ dst, const float* __restrict__ w,
                            float* deg, int E) {
    int e = blockIdx.x * blockDim.x + threadIdx.x;
    if (e < E) atomicAdd(&deg[dst[e]], w[e]);
}

__global__ void dinv_k(float* deg, int N) {
    int i = blockIdx.x * blockDim.x + threadIdx.x;
    if (i < N) { float d = deg[i]; deg[i] = d > 0.f ? rsqrtf(d) : 0.f; }
}

__global__ void norm_k(const int* __restrict__ src, const int* __restrict__ dst,
                       const float* __restrict__ w, const float* __restrict__ dinv,
                       float* norm, int E) {
    int e = blockIdx.x * blockDim.x + threadIdx.x;
    if (e < E) norm[e] = dinv[src[e]] * w[e] * dinv[dst[e]];
}

// Y[i,:] = dinv[i]^2 * X[i,:]   (F=128), one float4 per thread
__global__ void selfloop_k(const float* __restrict__ X, const float* __restrict__ dinv,
                           float* __restrict__ Y, int N) {
    int t = blockIdx.x * blockDim.x + threadIdx.x;
    int total = N * 32;             // 128/4 float4 per row
    if (t < total) {
        int i = t >> 5;
        float dv = dinv[i]; dv *= dv;
        float4 v = ((const float4*)X)[t];
        v.x *= dv; v.y *= dv; v.z *= dv; v.w *= dv;
        ((float4*)Y)[t] = v;
    }
}

// scatter-add: one wave (64 lanes) per edge, F=128 -> float2 per lane
__global__ void agg_edges_k(const int* __restrict__ src, const int* __restrict__ dst,
                            const float* __restrict__ norm,
                            const float* __restrict__ X, float* __restrict__ Y, int E) {
    int wid = (blockIdx.x * blockDim.x + threadIdx.x) >> 6;
    int lane = threadIdx.x & 63;
    if (wid >= E) return;
    int s = src[wid], d = dst[wid];
    float nv = norm[wid];
    float2 v = *(const float2*)&X[(size_t)s * 128 + lane * 2];
    float* yp = &Y[(size_t)d * 128 + lane * 2];
    atomicAdd(yp,     v.x * nv);
    atomicAdd(yp + 1, v.y * nv);
}

// z = relu(z0 + b2) in place + per-column partial sums for the head
__global__ void relu_colsum_k(float* __restrict__ Z, const float* __restrict__ b2,
                              float* __restrict__ zsum, int N) {
    int c = threadIdx.x;                 // 128 threads = 128 cols
    int nb = gridDim.x;
    int rpb = (N + nb - 1) / nb;
    int r0 = blockIdx.x * rpb;
    int r1 = min(N, r0 + rpb);
    float s = 0.f, bb = b2[c];
    for (int r = r0; r < r1; ++r) {
        float v = Z[(size_t)r * 128 + c] + bb;
        v = fmaxf(v, 0.f);
        Z[(size_t)r * 128 + c] = v;
        s += v;
    }
    atomicAdd(&zsum[c], s);
}

__global__ void head_k(const float* __restrict__ zsum, const float* __restrict__ Wh,
                       const float* __restrict__ bh, float* __restrict__ out, float invN) {
    __shared__ float red[128];
    int c = threadIdx.x;
    red[c] = zsum[c] * invN * Wh[c];
    __syncthreads();
    for (int s = 64; s > 0; s >>= 1) {
        if (c < s) red[c] += red[c + s];
        __syncthreads();
    }
    if (c == 0) out[0] = red[0] + bh[0];
}

// ---------------- generic tiled f32 GEMM with fused epilogues ----------------
// C[M,N] = concatK(A0|A1|A2) @ stackK(B0|B1) (+ bias0 + bias1) then epilogue.
// A sources switch at k = kb0 and k = kb1 (multiples of 16). B switches at kbB.

enum { EPI_NONE = 0, EPI_G = 1, EPI_SIG = 2, EPI_R = 3, EPI_H = 4 };

__global__ __launch_bounds__(256)
void gemm_k(const float* __restrict__ A0, const float* __restrict__ A1, const float* __restrict__ A2,
            int lda0, int lda1, int lda2, int kb0, int kb1, int K,
            const float* __restrict__ B0, const float* __restrict__ B1, int kbB, int ldb,
            const float* __restrict__ bias0, const float* __restrict__ bias1,
            const float* __restrict__ aux0, int ldx0, const float* __restrict__ aux1, int ldx1,
            float* __restrict__ C, int ldc, int M, int N, int epi)
{
    __shared__ float As[16][68];   // [k][m], stride 68 keeps float4 alignment
    __shared__ float Bs[16][64];   // [k][n]

    int tid = threadIdx.x;
    int row0 = blockIdx.x * 64, col0 = blockIdx.y * 64;
    int tx = tid & 15, ty = tid >> 4;

    int am = tid >> 2;          // A tile row 0..63
    int ak = (tid & 3) * 4;     // A tile k offset (float4)
    int bk = tid >> 4;          // B tile k 0..15
    int bnq = (tid & 15) * 4;   // B tile col offset

    float acc[4][4] = {};

    for (int kt = 0; kt < K; kt += 16) {
        // load A tile (virtual concat over k)
        int gm = row0 + am;
        int gk = kt + ak;
        const float* Ap; int la; int ko;
        if (gk < kb0)      { Ap = A0; la = lda0; ko = gk; }
        else if (gk < kb1) { Ap = A1; la = lda1; ko = gk - kb0; }
        else               { Ap = A2; la = lda2; ko = gk - kb1; }
        float4 av = make_float4(0.f, 0.f, 0.f, 0.f);
        if (gm < M) av = *(const float4*)&Ap[(size_t)gm * la + ko];
        As[ak + 0][am] = av.x; As[ak + 1][am] = av.y;
        As[ak + 2][am] = av.z; As[ak + 3][am] = av.w;

        // load B tile (stacked weights over k)
        int gkb = kt + bk;
        const float* Bp = B0; int kob = gkb;
        if (gkb >= kbB) { Bp = B1; kob = gkb - kbB; }
        float4 bv = *(const float4*)&Bp[(size_t)kob * ldb + col0 + bnq];
        *(float4*)&Bs[bk][bnq] = bv;

        __syncthreads();
        #pragma unroll
        for (int kk = 0; kk < 16; ++kk) {
            float4 a = *(const float4*)&As[kk][ty * 4];
            float4 b = *(const float4*)&Bs[kk][tx * 4];
            float avr[4] = {a.x, a.y, a.z, a.w};
            float bvr[4] = {b.x, b.y, b.z, b.w};
            #pragma unroll
            for (int i = 0; i < 4; ++i)
                #pragma unroll
                for (int j = 0; j < 4; ++j)
                    acc[i][j] = fmaf(avr[i], bvr[j], acc[i][j]);
        }
        __syncthreads();
    }

    // epilogue
    int crow = row0 + ty * 4;
    int ccol = col0 + tx * 4;
    float bcol[4];
    #pragma unroll
    for (int j = 0; j < 4; ++j) {
        int c = ccol + j;
        float bb = 0.f;
        if (bias0) bb += bias0[c];
        if (bias1) bb += bias1[c];
        bcol[j] = bb;
    }
    for (int i = 0; i < 4; ++i) {
        int r = crow + i;
        if (r >= M) break;
        for (int j = 0; j < 4; ++j) {
            int c = ccol + j;
            float v = acc[i][j] + bcol[j];
            float outv;
            if (epi == EPI_NONE)      outv = acc[i][j];
            else if (epi == EPI_G)    outv = fmaxf(v, 0.f) + aux0[(size_t)r * ldx0 + c];
            else if (epi == EPI_SIG)  outv = 1.f / (1.f + expf(-v));
            else if (epi == EPI_R)    outv = aux0[(size_t)r * ldx0 + c] * (1.f / (1.f + expf(-v)));
            else { // EPI_H: h = Z*prev_h + (1-Z)*tanh(acc+b)
                float zt = aux0[(size_t)r * ldx0 + c];
                outv = zt * aux1[(size_t)r * ldx1 + c] + (1.f - zt) * tanhf(v);
            }
            C[(size_t)r * ldc + c] = outv;
        }
    }
}

// ---------------- launch ----------------

extern "C" void kernel_launch(void* const* d_in, const int* in_sizes, int n_in,
                              void* d_out, int out_size, void* d_ws, size_t ws_size,
                              hipStream_t stream) {
    const float* x      = (const float*)d_in[0];
    const int*   ei     = (const int*)d_in[1];
    const float* ew     = (const float*)d_in[2];
    const float* prev_h = (const float*)d_in[3];
    const float* W1  = (const float*)d_in[4];  const float* b1  = (const float*)d_in[5];
    const float* W2  = (const float*)d_in[6];  const float* b2  = (const float*)d_in[7];
    const float* Wxz = (const float*)d_in[8];  const float* bxz = (const float*)d_in[9];
    const float* Whz = (const float*)d_in[10]; const float* bhz = (const float*)d_in[11];
    const float* Wxr = (const float*)d_in[12]; const float* bxr = (const float*)d_in[13];
    const float* Whr = (const float*)d_in[14]; const float* bhr = (const float*)d_in[15];
    const float* Wxh = (const float*)d_in[16]; const float* bxh = (const float*)d_in[17];
    const float* Whh = (const float*)d_in[18]; const float* bhh = (const float*)d_in[19];
    const float* Whead = (const float*)d_in[20]; const float* bhead = (const float*)d_in[21];

    const int N = in_sizes[0] / 128;
    const int E = in_sizes[2];
    const int* esrc = ei;
    const int* edst = ei + E;

    float* ws = (float*)d_ws;
    size_t o = 0;
    float* dinv = ws + o; o += (size_t)N;         // deg -> dinv (in place)
    float* norm = ws + o; o += (size_t)E;
    float* bufA = ws + o; o += (size_t)N * 256;   // g, then Z
    float* bufB = ws + o; o += (size_t)N * 256;   // t (lower half), then q = prev_h*R
    float* bufC = ws + o; o += (size_t)N * 128;   // gw2
    float* bufD = ws + o; o += (size_t)N * 128;   // z0 -> z
    float* zsum = ws + o; o += 128;
    float* t = bufB;                               // agg(x), dead before q is written
    float* hout = (float*)d_out + 1;               // output 1: h [N,256]

    const int TPB = 256;
    int gN = (N + TPB - 1) / TPB;
    int gE = (E + TPB - 1) / TPB;

    // normalization precompute
    init_deg_k<<<gN, TPB, 0, stream>>>(dinv, N);
    deg_edges_k<<<gE, TPB, 0, stream>>>(edst, ew, dinv, E);
    dinv_k<<<gN, TPB, 0, stream>>>(dinv, N);
    norm_k<<<gE, TPB, 0, stream>>>(esrc, edst, ew, dinv, norm, E);

    // t = agg(x)  [N,128]
    selfloop_k<<<(N * 32 + TPB - 1) / TPB, TPB, 0, stream>>>(x, dinv, t, N);
    agg_edges_k<<<(E + 3) / 4, TPB, 0, stream>>>(esrc, edst, norm, x, t, E);

    dim3 grid256((N + 63) / 64, 4);   // 256 output cols
    dim3 grid128((N + 63) / 64, 2);   // 128 output cols

    // g = relu(t@W1 + b1) + prev_h   [N,256]
    gemm_k<<<grid256, 256, 0, stream>>>(t, t, t, 128, 128, 128, 128, 128, 128,
                                        W1, W1, 128, 256,
                                        b1, nullptr, prev_h, 256, nullptr, 0,
                                        bufA, 256, N, 256, EPI_G);
    // gw2 = g@W2  [N,128]
    gemm_k<<<grid128, 256, 0, stream>>>(bufA, bufA, bufA, 256, 256, 256, 256, 256, 256,
                                        W2, W2, 256, 128,
                                        nullptr, nullptr, nullptr, 0, nullptr, 0,
                                        bufC, 128, N, 128, EPI_NONE);
    // z0 = agg(gw2)
    selfloop_k<<<(N * 32 + TPB - 1) / TPB, TPB, 0, stream>>>(bufC, dinv, bufD, N);
    agg_edges_k<<<(E + 3) / 4, TPB, 0, stream>>>(esrc, edst, norm, bufC, bufD, E);
    // z = relu(z0 + b2); column sums for head
    hipMemsetAsync(zsum, 0, 128 * sizeof(float), stream);
    relu_colsum_k<<<512, 128, 0, stream>>>(bufD, b2, zsum, N);
    head_k<<<1, 128, 0, stream>>>(zsum, Whead, bhead, (float*)d_out, 1.0f / (float)N);

    // GRU gates: A = [z | x | prev_h] (K=512), B = [Wx*; Wh*]
    // Z = sigmoid(...) -> bufA (g is dead)
    gemm_k<<<grid256, 256, 0, stream>>>(bufD, x, prev_h, 128, 128, 256, 128, 256, 512,
                                        Wxz, Whz, 256, 256,
                                        bxz, bhz, nullptr, 0, nullptr, 0,
                                        bufA, 256, N, 256, EPI_SIG);
    // q = prev_h * sigmoid(...) -> bufB (t is dead)
    gemm_k<<<grid256, 256, 0, stream>>>(bufD, x, prev_h, 128, 128, 256, 128, 256, 512,
                                        Wxr, Whr, 256, 256,
                                        bxr, bhr, prev_h, 256, nullptr, 0,
                                        bufB, 256, N, 256, EPI_R);
    // h = Z*prev_h + (1-Z)*tanh(xz@Wxh + q@Whh + b) -> d_out+1
    gemm_k<<<grid256, 256, 0, stream>>>(bufD, x, bufB, 128, 128, 256, 128, 256, 512,
                                        Wxh, Whh, 256, 256,
                                        bxh, bhh, bufA, 256, prev_h, 256,
                                        hout, 256, N, 256, EPI_H);
}

// Round 2
// 1061.393 us; speedup vs baseline: 1.9496x; 1.9496x over previous
//
#include <hip/hip_runtime.h>
#include <hip/hip_bf16.h>
#include <math.h>

// ---------------- normalization precompute ----------------

__global__ void init_deg_k(float* deg, int N) {
    int i = blockIdx.x * blockDim.x + threadIdx.x;
    if (i < N) deg[i] = 1.0f;   // self-loop weight
}

__global__ void deg_edges_k(const int* __restrict__ dst, const float* __restrict__ w,
                            float* deg, int E) {
    int e = blockIdx.x * blockDim.x + threadIdx.x;
    if (e < E) atomicAdd(&deg[dst[e]], w[e]);
}

__global__ void dinv_k(float* deg, int N) {
    int i = blockIdx.x * blockDim.x + threadIdx.x;
    if (i < N) { float d = deg[i]; deg[i] = d > 0.f ? rsqrtf(d) : 0.f; }
}

__global__ void norm_k(const int* __restrict__ src, const int* __restrict__ dst,
                       const float* __restrict__ w, const float* __restrict__ dinv,
                       float* norm, int E) {
    int e = blockIdx.x * blockDim.x + threadIdx.x;
    if (e < E) norm[e] = dinv[src[e]] * w[e] * dinv[dst[e]];
}

// ---------------- CSR build (by dst) ----------------

__global__ void cnt_edges_k(const int* __restrict__ dst, int* cnt, int E) {
    int e = blockIdx.x * blockDim.x + threadIdx.x;
    if (e < E) atomicAdd(&cnt[dst[e]], 1);
}

// single-block exclusive scan: rp[0..N], ofs[i] = exclusive prefix (fill cursor)
__global__ void scan_k(const int* __restrict__ cnt, int* __restrict__ rp,
                       int* __restrict__ ofs, int N) {
    __shared__ int buf[2][1024];
    __shared__ int carry_s;
    int tid = threadIdx.x;
    if (tid == 0) { carry_s = 0; rp[0] = 0; }
    __syncthreads();
    for (int base = 0; base < N; base += 1024) {
        int i = base + tid;
        int v = (i < N) ? cnt[i] : 0;
        int pp = 0;
        buf[0][tid] = v;
        __syncthreads();
        for (int o = 1; o < 1024; o <<= 1) {
            int nv = buf[pp][tid];
            if (tid >= o) nv += buf[pp][tid - o];
            buf[pp ^ 1][tid] = nv;
            pp ^= 1;
            __syncthreads();
        }
        int inc = buf[pp][tid];       // inclusive scan of this tile
        int c = carry_s;
        if (i < N) { rp[i + 1] = c + inc; ofs[i] = c + inc - v; }
        __syncthreads();
        if (tid == 1023) carry_s = c + inc;
        __syncthreads();
    }
}

__global__ void fill_csr_k(const int* __restrict__ src, const int* __restrict__ dst,
                           const float* __restrict__ norm, int* ofs,
                           int* __restrict__ csr_src, float* __restrict__ csr_norm, int E) {
    int e = blockIdx.x * blockDim.x + threadIdx.x;
    if (e < E) {
        int p = atomicAdd(&ofs[dst[e]], 1);
        csr_src[p] = src[e];
        csr_norm[p] = norm[e];
    }
}

// ---------------- CSR gather aggregation ----------------
// one wave per dst node; F=128 -> float2 per lane; write-once output.
// EPI: 0 = plain (agg1), 1 = relu(acc + b) (agg2)
template <int EPI>
__global__ void agg_csr_k(const int* __restrict__ rp, const int* __restrict__ csr_src,
                          const float* __restrict__ csr_norm, const float* __restrict__ X,
                          const float* __restrict__ dinv, const float* __restrict__ bias,
                          float* __restrict__ Y, int N) {
    int wid = (blockIdx.x * blockDim.x + threadIdx.x) >> 6;
    int lane = threadIdx.x & 63;
    if (wid >= N) return;
    float dv = dinv[wid]; dv *= dv;                 // self-loop: dinv^2 * 1.0
    float2 acc = *(const float2*)&X[(size_t)wid * 128 + lane * 2];
    acc.x *= dv; acc.y *= dv;
    int p = rp[wid], pend = rp[wid + 1];
    // 4-wide unroll for load-latency overlap
    for (; p + 4 <= pend; p += 4) {
        int s0 = csr_src[p], s1 = csr_src[p + 1], s2 = csr_src[p + 2], s3 = csr_src[p + 3];
        float n0 = csr_norm[p], n1 = csr_norm[p + 1], n2 = csr_norm[p + 2], n3 = csr_norm[p + 3];
        float2 v0 = *(const float2*)&X[(size_t)s0 * 128 + lane * 2];
        float2 v1 = *(const float2*)&X[(size_t)s1 * 128 + lane * 2];
        float2 v2 = *(const float2*)&X[(size_t)s2 * 128 + lane * 2];
        float2 v3 = *(const float2*)&X[(size_t)s3 * 128 + lane * 2];
        acc.x = fmaf(v0.x, n0, acc.x); acc.y = fmaf(v0.y, n0, acc.y);
        acc.x = fmaf(v1.x, n1, acc.x); acc.y = fmaf(v1.y, n1, acc.y);
        acc.x = fmaf(v2.x, n2, acc.x); acc.y = fmaf(v2.y, n2, acc.y);
        acc.x = fmaf(v3.x, n3, acc.x); acc.y = fmaf(v3.y, n3, acc.y);
    }
    for (; p < pend; ++p) {
        int s = csr_src[p]; float nv = csr_norm[p];
        float2 v = *(const float2*)&X[(size_t)s * 128 + lane * 2];
        acc.x = fmaf(v.x, nv, acc.x); acc.y = fmaf(v.y, nv, acc.y);
    }
    if (EPI == 1) {
        float b0 = bias[lane * 2], b1 = bias[lane * 2 + 1];
        acc.x = fmaxf(acc.x + b0, 0.f);
        acc.y = fmaxf(acc.y + b1, 0.f);
    }
    *(float2*)&Y[(size_t)wid * 128 + lane * 2] = acc;
}

// ---------------- head ----------------

__global__ void colsum_k(const float* __restrict__ Z, float* __restrict__ zsum, int N) {
    int c = threadIdx.x;                 // 128 threads = 128 cols
    int nb = gridDim.x;
    int rpb = (N + nb - 1) / nb;
    int r0 = blockIdx.x * rpb;
    int r1 = min(N, r0 + rpb);
    float s = 0.f;
    for (int r = r0; r < r1; ++r) s += Z[(size_t)r * 128 + c];
    atomicAdd(&zsum[c], s);
}

__global__ void head_k(const float* __restrict__ zsum, const float* __restrict__ Wh,
                       const float* __restrict__ bh, float* __restrict__ out, float invN) {
    __shared__ float red[128];
    int c = threadIdx.x;
    red[c] = zsum[c] * invN * Wh[c];
    __syncthreads();
    for (int s = 64; s > 0; s >>= 1) {
        if (c < s) red[c] += red[c + s];
        __syncthreads();
    }
    if (c == 0) out[0] = red[0] + bh[0];
}

// ---------------- generic tiled f32 GEMM with fused epilogues ----------------

enum { EPI_NONE = 0, EPI_G = 1, EPI_SIG = 2, EPI_R = 3, EPI_H = 4 };

__global__ __launch_bounds__(256)
void gemm_k(const float* __restrict__ A0, const float* __restrict__ A1, const float* __restrict__ A2,
            int lda0, int lda1, int lda2, int kb0, int kb1, int K,
            const float* __restrict__ B0, const float* __restrict__ B1, int kbB, int ldb,
            const float* __restrict__ bias0, const float* __restrict__ bias1,
            const float* __restrict__ aux0, int ldx0, const float* __restrict__ aux1, int ldx1,
            float* __restrict__ C, int ldc, int M, int N, int epi)
{
    __shared__ float As[16][68];
    __shared__ float Bs[16][64];

    int tid = threadIdx.x;
    int row0 = blockIdx.x * 64, col0 = blockIdx.y * 64;
    int tx = tid & 15, ty = tid >> 4;

    int am = tid >> 2;
    int ak = (tid & 3) * 4;
    int bk = tid >> 4;
    int bnq = (tid & 15) * 4;

    float acc[4][4] = {};

    for (int kt = 0; kt < K; kt += 16) {
        int gm = row0 + am;
        int gk = kt + ak;
        const float* Ap; int la; int ko;
        if (gk < kb0)      { Ap = A0; la = lda0; ko = gk; }
        else if (gk < kb1) { Ap = A1; la = lda1; ko = gk - kb0; }
        else               { Ap = A2; la = lda2; ko = gk - kb1; }
        float4 av = make_float4(0.f, 0.f, 0.f, 0.f);
        if (gm < M) av = *(const float4*)&Ap[(size_t)gm * la + ko];
        As[ak + 0][am] = av.x; As[ak + 1][am] = av.y;
        As[ak + 2][am] = av.z; As[ak + 3][am] = av.w;

        int gkb = kt + bk;
        const float* Bp = B0; int kob = gkb;
        if (gkb >= kbB) { Bp = B1; kob = gkb - kbB; }
        float4 bv = *(const float4*)&Bp[(size_t)kob * ldb + col0 + bnq];
        *(float4*)&Bs[bk][bnq] = bv;

        __syncthreads();
        #pragma unroll
        for (int kk = 0; kk < 16; ++kk) {
            float4 a = *(const float4*)&As[kk][ty * 4];
            float4 b = *(const float4*)&Bs[kk][tx * 4];
            float avr[4] = {a.x, a.y, a.z, a.w};
            float bvr[4] = {b.x, b.y, b.z, b.w};
            #pragma unroll
            for (int i = 0; i < 4; ++i)
                #pragma unroll
                for (int j = 0; j < 4; ++j)
                    acc[i][j] = fmaf(avr[i], bvr[j], acc[i][j]);
        }
        __syncthreads();
    }

    int crow = row0 + ty * 4;
    int ccol = col0 + tx * 4;
    float bcol[4];
    #pragma unroll
    for (int j = 0; j < 4; ++j) {
        int c = ccol + j;
        float bb = 0.f;
        if (bias0) bb += bias0[c];
        if (bias1) bb += bias1[c];
        bcol[j] = bb;
    }
    for (int i = 0; i < 4; ++i) {
        int r = crow + i;
        if (r >= M) break;
        for (int j = 0; j < 4; ++j) {
            int c = ccol + j;
            float v = acc[i][j] + bcol[j];
            float outv;
            if (epi == EPI_NONE)      outv = acc[i][j];
            else if (epi == EPI_G)    outv = fmaxf(v, 0.f) + aux0[(size_t)r * ldx0 + c];
            else if (epi == EPI_SIG)  outv = 1.f / (1.f + expf(-v));
            else if (epi == EPI_R)    outv = aux0[(size_t)r * ldx0 + c] * (1.f / (1.f + expf(-v)));
            else {
                float zt = aux0[(size_t)r * ldx0 + c];
                outv = zt * aux1[(size_t)r * ldx1 + c] + (1.f - zt) * tanhf(v);
            }
            C[(size_t)r * ldc + c] = outv;
        }
    }
}

// ---------------- launch ----------------

extern "C" void kernel_launch(void* const* d_in, const int* in_sizes, int n_in,
                              void* d_out, int out_size, void* d_ws, size_t ws_size,
                              hipStream_t stream) {
    const float* x      = (const float*)d_in[0];
    const int*   ei     = (const int*)d_in[1];
    const float* ew     = (const float*)d_in[2];
    const float* prev_h = (const float*)d_in[3];
    const float* W1  = (const float*)d_in[4];  const float* b1  = (const float*)d_in[5];
    const float* W2  = (const float*)d_in[6];  const float* b2  = (const float*)d_in[7];
    const float* Wxz = (const float*)d_in[8];  const float* bxz = (const float*)d_in[9];
    const float* Whz = (const float*)d_in[10]; const float* bhz = (const float*)d_in[11];
    const float* Wxr = (const float*)d_in[12]; const float* bxr = (const float*)d_in[13];
    const float* Whr = (const float*)d_in[14]; const float* bhr = (const float*)d_in[15];
    const float* Wxh = (const float*)d_in[16]; const float* bxh = (const float*)d_in[17];
    const float* Whh = (const float*)d_in[18]; const float* bhh = (const float*)d_in[19];
    const float* Whead = (const float*)d_in[20]; const float* bhead = (const float*)d_in[21];

    const int N = in_sizes[0] / 128;
    const int E = in_sizes[2];
    const int* esrc = ei;
    const int* edst = ei + E;

    float* ws = (float*)d_ws;
    size_t o = 0;
    float* dinv   = ws + o; o += (size_t)N;
    float* norm   = ws + o; o += (size_t)E;
    int*   cnt    = (int*)(ws + o); o += (size_t)N;        // reused as fill cursor
    int*   rowp   = (int*)(ws + o); o += (size_t)N + 1;
    float* bufA   = ws + o; o += (size_t)N * 256;          // g, then Z
    float* bufB   = ws + o; o += (size_t)N * 256;          // t + csr arrays, then q
    float* bufC   = ws + o; o += (size_t)N * 128;          // gw2
    float* bufD   = ws + o; o += (size_t)N * 128;          // z
    float* zsum   = ws + o; o += 128;

    // alias CSR arrays into bufB's upper region: dead once q is written (after last agg)
    float* t        = bufB;                                 // [N,128]
    int*   csr_src  = (int*)(bufB + (size_t)N * 128);       // [E]
    float* csr_norm = bufB + (size_t)N * 128 + E;           // [E]
    float* hout = (float*)d_out + 1;                        // output 1: h [N,256]

    const int TPB = 256;
    int gN = (N + TPB - 1) / TPB;
    int gE = (E + TPB - 1) / TPB;
    int gAgg = (N * 64 + TPB - 1) / TPB;   // one wave per node

    // normalization
    init_deg_k<<<gN, TPB, 0, stream>>>(dinv, N);
    deg_edges_k<<<gE, TPB, 0, stream>>>(edst, ew, dinv, E);
    dinv_k<<<gN, TPB, 0, stream>>>(dinv, N);
    norm_k<<<gE, TPB, 0, stream>>>(esrc, edst, ew, dinv, norm, E);

    // CSR build (by dst)
    hipMemsetAsync(cnt, 0, (size_t)N * sizeof(int), stream);
    cnt_edges_k<<<gE, TPB, 0, stream>>>(edst, cnt, E);
    scan_k<<<1, 1024, 0, stream>>>(cnt, rowp, cnt, N);      // cnt becomes fill cursor
    fill_csr_k<<<gE, TPB, 0, stream>>>(esrc, edst, norm, cnt, csr_src, csr_norm, E);

    // t = agg(x)  [N,128]
    agg_csr_k<0><<<gAgg, TPB, 0, stream>>>(rowp, csr_src, csr_norm, x, dinv, nullptr, t, N);

    dim3 grid256((N + 63) / 64, 4);
    dim3 grid128((N + 63) / 64, 2);

    // g = relu(t@W1 + b1) + prev_h
    gemm_k<<<grid256, 256, 0, stream>>>(t, t, t, 128, 128, 128, 128, 128, 128,
                                        W1, W1, 128, 256,
                                        b1, nullptr, prev_h, 256, nullptr, 0,
                                        bufA, 256, N, 256, EPI_G);
    // gw2 = g@W2
    gemm_k<<<grid128, 256, 0, stream>>>(bufA, bufA, bufA, 256, 256, 256, 256, 256, 256,
                                        W2, W2, 256, 128,
                                        nullptr, nullptr, nullptr, 0, nullptr, 0,
                                        bufC, 128, N, 128, EPI_NONE);
    // z = relu(agg(gw2) + b2)   (bias+relu fused into gather)
    agg_csr_k<1><<<gAgg, TPB, 0, stream>>>(rowp, csr_src, csr_norm, bufC, dinv, b2, bufD, N);

    // head
    hipMemsetAsync(zsum, 0, 128 * sizeof(float), stream);
    colsum_k<<<512, 128, 0, stream>>>(bufD, zsum, N);
    head_k<<<1, 128, 0, stream>>>(zsum, Whead, bhead, (float*)d_out, 1.0f / (float)N);

    // GRU gates: A = [z | x | prev_h] (K=512), B = [Wx*; Wh*]
    gemm_k<<<grid256, 256, 0, stream>>>(bufD, x, prev_h, 128, 128, 256, 128, 256, 512,
                                        Wxz, Whz, 256, 256,
                                        bxz, bhz, nullptr, 0, nullptr, 0,
                                        bufA, 256, N, 256, EPI_SIG);
    gemm_k<<<grid256, 256, 0, stream>>>(bufD, x, prev_h, 128, 128, 256, 128, 256, 512,
                                        Wxr, Whr, 256, 256,
                                        bxr, bhr, prev_h, 256, nullptr, 0,
                                        bufB, 256, N, 256, EPI_R);
    gemm_k<<<grid256, 256, 0, stream>>>(bufD, x, bufB, 128, 128, 256, 128, 256, 512,
                                        Wxh, Whh, 256, 256,
                                        bxh, bhh, bufA, 256, prev_h, 256,
                                        hout, 256, N, 256, EPI_H);
}

// Round 3
// 681.138 us; speedup vs baseline: 3.0379x; 1.5583x over previous
//
#include <hip/hip_runtime.h>
#include <math.h>

typedef __attribute__((ext_vector_type(8))) short short8;   // 8 bf16 = 4 VGPR
typedef __attribute__((ext_vector_type(4))) float f32x4;

__device__ inline unsigned short f2bf(float f) {
    unsigned int u = __float_as_uint(f);
    u += 0x7fffu + ((u >> 16) & 1u);          // RNE
    return (unsigned short)(u >> 16);
}
__device__ inline float bf2f(unsigned int h) { return __uint_as_float(h << 16); }

// ---------------- degree / CSR ----------------

__global__ void init_k(float* deg, int* cnt, int N) {
    int i = blockIdx.x * blockDim.x + threadIdx.x;
    if (i < N) { deg[i] = 1.0f; cnt[i] = 0; }
}

__global__ void deg_cnt_k(const int* __restrict__ dst, const float* __restrict__ w,
                          float* deg, int* cnt, int E) {
    int e = blockIdx.x * blockDim.x + threadIdx.x;
    if (e < E) { int d = dst[e]; atomicAdd(&deg[d], w[e]); atomicAdd(&cnt[d], 1); }
}

__global__ void dinv_k(float* deg, int N) {
    int i = blockIdx.x * blockDim.x + threadIdx.x;
    if (i < N) { float d = deg[i]; deg[i] = d > 0.f ? rsqrtf(d) : 0.f; }
}

__global__ void scan_k(const int* __restrict__ cnt, int* __restrict__ rp,
                       int* __restrict__ ofs, int N) {
    __shared__ int buf[2][1024];
    __shared__ int carry_s;
    int tid = threadIdx.x;
    if (tid == 0) { carry_s = 0; rp[0] = 0; }
    __syncthreads();
    for (int base = 0; base < N; base += 1024) {
        int i = base + tid;
        int v = (i < N) ? cnt[i] : 0;
        int pp = 0;
        buf[0][tid] = v;
        __syncthreads();
        for (int o = 1; o < 1024; o <<= 1) {
            int nv = buf[pp][tid];
            if (tid >= o) nv += buf[pp][tid - o];
            buf[pp ^ 1][tid] = nv;
            pp ^= 1;
            __syncthreads();
        }
        int inc = buf[pp][tid];
        int c = carry_s;
        if (i < N) { rp[i + 1] = c + inc; ofs[i] = c + inc - v; }
        __syncthreads();
        if (tid == 1023) carry_s = c + inc;
        __syncthreads();
    }
}

__global__ void fill_csr_k(const int* __restrict__ src, const int* __restrict__ dst,
                           const float* __restrict__ w, const float* __restrict__ dinv,
                           int* ofs, int* __restrict__ csr_src, float* __restrict__ csr_norm, int E) {
    int e = blockIdx.x * blockDim.x + threadIdx.x;
    if (e < E) {
        int s = src[e], d = dst[e];
        int p = atomicAdd(&ofs[d], 1);
        csr_src[p] = s;
        csr_norm[p] = dinv[s] * w[e] * dinv[d];
    }
}

// ---------------- conversions ----------------

__global__ void cvt_x_k(const float* __restrict__ x, unsigned short* __restrict__ zx, int N) {
    int t = blockIdx.x * blockDim.x + threadIdx.x;
    if (t >= N * 32) return;
    int r = t >> 5, c4 = (t & 31) * 4;
    float4 v = *(const float4*)&x[(size_t)r * 128 + c4];
    uint2 o;
    o.x = (unsigned)f2bf(v.x) | ((unsigned)f2bf(v.y) << 16);
    o.y = (unsigned)f2bf(v.z) | ((unsigned)f2bf(v.w) << 16);
    *(uint2*)&zx[(size_t)r * 256 + 128 + c4] = o;
}

__global__ void cvt_ph_k(const float* __restrict__ ph, unsigned short* __restrict__ d, int N) {
    int t = blockIdx.x * blockDim.x + threadIdx.x;
    if (t >= N * 64) return;
    int r = t >> 6, c4 = (t & 63) * 4;
    float4 v = *(const float4*)&ph[(size_t)r * 256 + c4];
    uint2 o;
    o.x = (unsigned)f2bf(v.x) | ((unsigned)f2bf(v.y) << 16);
    o.y = (unsigned)f2bf(v.z) | ((unsigned)f2bf(v.w) << 16);
    *(uint2*)&d[(size_t)r * 256 + c4] = o;
}

// all weights -> bf16, transposed to Bt[n][k]
__global__ void cvtw_k(const float* W1, const float* W2,
                       const float* Wxz, const float* Whz, const float* Wxr, const float* Whr,
                       const float* Wxh, const float* Whh,
                       unsigned short* Bt1, unsigned short* Bt2,
                       unsigned short* BtZR, unsigned short* BtH) {
    int t = blockIdx.x * blockDim.x + threadIdx.x;
    if (t < 32768) { int k = t >> 8, n = t & 255; Bt1[(size_t)n * 128 + k] = f2bf(W1[t]); return; }
    t -= 32768;
    if (t < 32768) { int k = t >> 7, n = t & 127; Bt2[(size_t)n * 256 + k] = f2bf(W2[t]); return; }
    t -= 32768;
    if (t < 65536) { int k = t >> 8, n = t & 255; BtZR[(size_t)n * 512 + k] = f2bf(Wxz[t]); return; }
    t -= 65536;
    if (t < 65536) { int k = t >> 8, n = t & 255; BtZR[(size_t)n * 512 + 256 + k] = f2bf(Whz[t]); return; }
    t -= 65536;
    if (t < 65536) { int k = t >> 8, n = t & 255; BtZR[(size_t)(256 + n) * 512 + k] = f2bf(Wxr[t]); return; }
    t -= 65536;
    if (t < 65536) { int k = t >> 8, n = t & 255; BtZR[(size_t)(256 + n) * 512 + 256 + k] = f2bf(Whr[t]); return; }
    t -= 65536;
    if (t < 65536) { int k = t >> 8, n = t & 255; BtH[(size_t)n * 512 + k] = f2bf(Wxh[t]); return; }
    t -= 65536;
    if (t < 65536) { int k = t >> 8, n = t & 255; BtH[(size_t)n * 512 + 256 + k] = f2bf(Whh[t]); }
}

__global__ void bias_fuse_k(const float* bxz, const float* bhz, const float* bxr, const float* bhr,
                            const float* bxh, const float* bhh, float* bZR, float* bH) {
    int t = blockIdx.x * blockDim.x + threadIdx.x;
    if (t < 256)       bZR[t] = bxz[t] + bhz[t];
    else if (t < 512)  bZR[t] = bxr[t - 256] + bhr[t - 256];
    else if (t < 768)  bH[t - 512] = bxh[t - 512] + bhh[t - 512];
}

// ---------------- CSR gather (bf16 in, f32 accum, bf16 out) ----------------
// one wave per node, 2 cols/lane. EPI 1: relu(acc+bias)
template <int EPI>
__global__ void agg_bf_k(const int* __restrict__ rp, const int* __restrict__ cs,
                         const float* __restrict__ cn,
                         const unsigned short* __restrict__ X, int ldx2, int xo2,
                         const float* __restrict__ dinv, const float* __restrict__ bias,
                         unsigned short* __restrict__ Y, int ldy2, int yo2, int N) {
    int wid = (blockIdx.x * blockDim.x + threadIdx.x) >> 6;
    int lane = threadIdx.x & 63;
    if (wid >= N) return;
    const unsigned int* Xu = (const unsigned int*)X;
    float dv = dinv[wid]; dv *= dv;
    unsigned int sv = Xu[(size_t)wid * ldx2 + xo2 + lane];
    float ax = bf2f(sv & 0xffffu) * dv, ay = bf2f(sv >> 16) * dv;
    int p = rp[wid], pe = rp[wid + 1];
    for (; p + 4 <= pe; p += 4) {
        int s0 = cs[p], s1 = cs[p+1], s2 = cs[p+2], s3 = cs[p+3];
        float n0 = cn[p], n1 = cn[p+1], n2 = cn[p+2], n3 = cn[p+3];
        unsigned int v0 = Xu[(size_t)s0 * ldx2 + xo2 + lane];
        unsigned int v1 = Xu[(size_t)s1 * ldx2 + xo2 + lane];
        unsigned int v2 = Xu[(size_t)s2 * ldx2 + xo2 + lane];
        unsigned int v3 = Xu[(size_t)s3 * ldx2 + xo2 + lane];
        ax = fmaf(bf2f(v0 & 0xffffu), n0, ax); ay = fmaf(bf2f(v0 >> 16), n0, ay);
        ax = fmaf(bf2f(v1 & 0xffffu), n1, ax); ay = fmaf(bf2f(v1 >> 16), n1, ay);
        ax = fmaf(bf2f(v2 & 0xffffu), n2, ax); ay = fmaf(bf2f(v2 >> 16), n2, ay);
        ax = fmaf(bf2f(v3 & 0xffffu), n3, ax); ay = fmaf(bf2f(v3 >> 16), n3, ay);
    }
    for (; p < pe; ++p) {
        int s = cs[p]; float nv = cn[p];
        unsigned int v = Xu[(size_t)s * ldx2 + xo2 + lane];
        ax = fmaf(bf2f(v & 0xffffu), nv, ax); ay = fmaf(bf2f(v >> 16), nv, ay);
    }
    if (EPI == 1) {
        ax = fmaxf(ax + bias[lane * 2], 0.f);
        ay = fmaxf(ay + bias[lane * 2 + 1], 0.f);
    }
    unsigned int o = (unsigned)f2bf(ax) | ((unsigned)f2bf(ay) << 16);
    ((unsigned int*)Y)[(size_t)wid * ldy2 + yo2 + lane] = o;
}

// ---------------- head ----------------

__global__ void colsum_bf_k(const unsigned short* __restrict__ Z, float* zsum, int N) {
    int c = threadIdx.x;                 // 128 cols
    int rpb = (N + gridDim.x - 1) / gridDim.x;
    int r0 = blockIdx.x * rpb, r1 = min(N, r0 + rpb);
    float s = 0.f;
    for (int r = r0; r < r1; ++r) s += bf2f((unsigned int)Z[(size_t)r * 256 + c]);
    atomicAdd(&zsum[c], s);
}

__global__ void head_k(const float* __restrict__ zsum, const float* __restrict__ Wh,
                       const float* __restrict__ bh, float* __restrict__ out, float invN) {
    __shared__ float red[128];
    int c = threadIdx.x;
    red[c] = zsum[c] * invN * Wh[c];
    __syncthreads();
    for (int s = 64; s > 0; s >>= 1) {
        if (c < s) red[c] += red[c + s];
        __syncthreads();
    }
    if (c == 0) out[0] = red[0] + bh[0];
}

// ---------------- bf16 MFMA GEMM, 128x128 tile, fused epilogues ----------------
// C = concatK(A0|A1) @ Bt^T ; Bt is [Ncols][K] bf16 (pre-transposed weights).
// LDS layout per operand: slot(r,c) = r*4 + (c ^ (r&3)), 8 bf16 per slot.

enum { EPI_G = 0, EPI_P = 1, EPI_ZR = 2, EPI_H = 3 };

__global__ __launch_bounds__(256)
void mm_bf16_k(const unsigned short* __restrict__ A0, const unsigned short* __restrict__ A1,
               int lda0, int lda1, int kb,
               const unsigned short* __restrict__ Bt, int K, int M,
               const float* __restrict__ x0, const float* __restrict__ x1,
               const float* __restrict__ x2,
               void* __restrict__ out, void* __restrict__ out2, int epi) {
    __shared__ unsigned short Als[4096];   // 8 KB
    __shared__ unsigned short Bls[4096];

    int t = threadIdx.x;
    int row0 = blockIdx.x * 128, col0 = blockIdx.y * 128;
    int w = t >> 6, lane = t & 63;
    int wr = w >> 1, wc = w & 1;
    int m15 = lane & 15, g = lane >> 4;

    f32x4 acc[4][4];
    #pragma unroll
    for (int i = 0; i < 4; ++i)
        #pragma unroll
        for (int j = 0; j < 4; ++j)
            #pragma unroll
            for (int q = 0; q < 4; ++q) acc[i][j][q] = 0.f;

    for (int kt = 0; kt < K; kt += 32) {
        const unsigned short* Ap = A0; int lda = lda0; int ka = kt;
        if (kt >= kb) { Ap = A1; lda = lda1; ka = kt - kb; }
        #pragma unroll
        for (int i = 0; i < 2; ++i) {
            int idx = i * 256 + t;
            int r = idx >> 2, c = idx & 3;
            int gr = row0 + r; gr = gr < M ? gr : M - 1;
            uint4 va = *(const uint4*)&Ap[(size_t)gr * lda + ka + c * 8];
            *(uint4*)&Als[((r << 2) + (c ^ (r & 3))) << 3] = va;
            uint4 vb = *(const uint4*)&Bt[(size_t)(col0 + r) * K + kt + c * 8];
            *(uint4*)&Bls[((r << 2) + (c ^ (r & 3))) << 3] = vb;
        }
        __syncthreads();
        short8 af[4], bfr[4];
        #pragma unroll
        for (int ms = 0; ms < 4; ++ms) {
            int rt = wr * 64 + ms * 16 + m15;
            af[ms] = *(const short8*)&Als[((rt << 2) + (g ^ (rt & 3))) << 3];
        }
        #pragma unroll
        for (int ns = 0; ns < 4; ++ns) {
            int nt = wc * 64 + ns * 16 + m15;
            bfr[ns] = *(const short8*)&Bls[((nt << 2) + (g ^ (nt & 3))) << 3];
        }
        #pragma unroll
        for (int ms = 0; ms < 4; ++ms)
            #pragma unroll
            for (int ns = 0; ns < 4; ++ns)
                acc[ms][ns] = __builtin_amdgcn_mfma_f32_16x16x32_bf16(af[ms], bfr[ns], acc[ms][ns], 0, 0, 0);
        __syncthreads();
    }

    // epilogue: row = row0 + wr*64 + ms*16 + (lane>>4)*4 + i; col = col0 + wc*64 + ns*16 + (lane&15)
    int r4 = (lane >> 4) * 4;
    #pragma unroll
    for (int ms = 0; ms < 4; ++ms) {
        #pragma unroll
        for (int ns = 0; ns < 4; ++ns) {
            int col = col0 + wc * 64 + ns * 16 + m15;
            #pragma unroll
            for (int i = 0; i < 4; ++i) {
                int row = row0 + wr * 64 + ms * 16 + r4 + i;
                if (row >= M) continue;
                float v = acc[ms][ns][i];
                if (epi == EPI_G) {
                    float val = fmaxf(v + x0[col], 0.f) + x1[(size_t)row * 256 + col];
                    ((unsigned short*)out)[(size_t)row * 256 + col] = f2bf(val);
                } else if (epi == EPI_P) {
                    ((unsigned short*)out)[(size_t)row * 128 + col] = f2bf(v);
                } else if (epi == EPI_ZR) {
                    float s = 1.f / (1.f + __expf(-(v + x0[col])));
                    if (col < 256) {
                        ((float*)out)[(size_t)row * 256 + col] = s;
                    } else {
                        int c2 = col - 256;
                        ((unsigned short*)out2)[(size_t)row * 256 + c2] =
                            f2bf(x1[(size_t)row * 256 + c2] * s);
                    }
                } else {  // EPI_H
                    float s = v + x0[col];
                    float e = __expf(2.f * s);
                    float ht = 1.f - 2.f / (e + 1.f);
                    float Zt = x2[(size_t)row * 256 + col];
                    ((float*)out)[(size_t)row * 256 + col] =
                        Zt * x1[(size_t)row * 256 + col] + (1.f - Zt) * ht;
                }
            }
        }
    }
}

// ---------------- launch ----------------

extern "C" void kernel_launch(void* const* d_in, const int* in_sizes, int n_in,
                              void* d_out, int out_size, void* d_ws, size_t ws_size,
                              hipStream_t stream) {
    const float* x      = (const float*)d_in[0];
    const int*   ei     = (const int*)d_in[1];
    const float* ew     = (const float*)d_in[2];
    const float* prev_h = (const float*)d_in[3];
    const float* W1  = (const float*)d_in[4];  const float* b1  = (const float*)d_in[5];
    const float* W2  = (const float*)d_in[6];  const float* b2  = (const float*)d_in[7];
    const float* Wxz = (const float*)d_in[8];  const float* bxz = (const float*)d_in[9];
    const float* Whz = (const float*)d_in[10]; const float* bhz = (const float*)d_in[11];
    const float* Wxr = (const float*)d_in[12]; const float* bxr = (const float*)d_in[13];
    const float* Whr = (const float*)d_in[14]; const float* bhr = (const float*)d_in[15];
    const float* Wxh = (const float*)d_in[16]; const float* bxh = (const float*)d_in[17];
    const float* Whh = (const float*)d_in[18]; const float* bhh = (const float*)d_in[19];
    const float* Whead = (const float*)d_in[20]; const float* bhead = (const float*)d_in[21];

    const int N = in_sizes[0] / 128;
    const int E = in_sizes[2];
    const int* esrc = ei;
    const int* edst = ei + E;

    float* ws = (float*)d_ws;
    size_t o = 0;
    float* dinv     = ws + o; o += (size_t)N;
    int*   cnt      = (int*)(ws + o); o += (size_t)N;        // reused as fill cursor
    int*   rowp     = (int*)(ws + o); o += (size_t)N + 4;
    int*   csr_src  = (int*)(ws + o); o += (size_t)E;
    float* csr_norm = ws + o; o += (size_t)E;
    unsigned short* zx  = (unsigned short*)(ws + o); o += (size_t)N * 128;  // [N,256]: z | x
    unsigned short* phb = (unsigned short*)(ws + o); o += (size_t)N * 128;  // prev_h bf16 [N,256]
    unsigned short* buf1 = (unsigned short*)(ws + o); o += (size_t)N * 128; // t -> gw2 -> q
    float* bufZ     = ws + o; o += (size_t)N * 256;          // g_bf (aliased) -> Z f32
    unsigned short* Bt1  = (unsigned short*)(ws + o); o += 16384;
    unsigned short* Bt2  = (unsigned short*)(ws + o); o += 16384;
    unsigned short* BtZR = (unsigned short*)(ws + o); o += 131072;
    unsigned short* BtH  = (unsigned short*)(ws + o); o += 65536;
    float* bZR      = ws + o; o += 512;
    float* bH       = ws + o; o += 256;
    float* zsum     = ws + o; o += 128;

    unsigned short* g_bf = (unsigned short*)bufZ;   // [N,256] bf16, dead before Z written
    float* hout = (float*)d_out + 1;                // output 1: h [N,256]

    const int TPB = 256;
    int gN = (N + TPB - 1) / TPB;
    int gE = (E + TPB - 1) / TPB;
    int gAgg = (N * 64 + TPB - 1) / TPB;
    int nb = (N + 127) / 128;

    // norm + CSR
    init_k<<<gN, TPB, 0, stream>>>(dinv, cnt, N);
    deg_cnt_k<<<gE, TPB, 0, stream>>>(edst, ew, dinv, cnt, E);
    dinv_k<<<gN, TPB, 0, stream>>>(dinv, N);
    scan_k<<<1, 1024, 0, stream>>>(cnt, rowp, cnt, N);
    fill_csr_k<<<gE, TPB, 0, stream>>>(esrc, edst, ew, dinv, cnt, csr_src, csr_norm, E);

    // conversions
    cvt_x_k<<<(N * 32 + TPB - 1) / TPB, TPB, 0, stream>>>(x, zx, N);
    cvt_ph_k<<<(N * 64 + TPB - 1) / TPB, TPB, 0, stream>>>(prev_h, phb, N);
    cvtw_k<<<1792, TPB, 0, stream>>>(W1, W2, Wxz, Whz, Wxr, Whr, Wxh, Whh, Bt1, Bt2, BtZR, BtH);
    bias_fuse_k<<<3, TPB, 0, stream>>>(bxz, bhz, bxr, bhr, bxh, bhh, bZR, bH);

    // t = agg(x)  (reads x part of zx, writes buf1 [N,128])
    agg_bf_k<0><<<gAgg, TPB, 0, stream>>>(rowp, csr_src, csr_norm, zx, 128, 64, dinv,
                                          nullptr, buf1, 64, 0, N);

    // g = relu(t@W1 + b1) + prev_h  -> g_bf [N,256]
    mm_bf16_k<<<dim3(nb, 2), 256, 0, stream>>>(buf1, buf1, 128, 128, 128, Bt1, 128, N,
                                               b1, prev_h, nullptr, g_bf, nullptr, EPI_G);
    // gw2 = g@W2 -> buf1 [N,128]
    mm_bf16_k<<<dim3(nb, 1), 256, 0, stream>>>(g_bf, g_bf, 256, 256, 256, Bt2, 256, N,
                                               nullptr, nullptr, nullptr, buf1, nullptr, EPI_P);
    // z = relu(agg(gw2) + b2) -> zx cols 0..127
    agg_bf_k<1><<<gAgg, TPB, 0, stream>>>(rowp, csr_src, csr_norm, buf1, 64, 0, dinv,
                                          b2, zx, 128, 0, N);

    // head
    hipMemsetAsync(zsum, 0, 128 * sizeof(float), stream);
    colsum_bf_k<<<512, 128, 0, stream>>>(zx, zsum, N);
    head_k<<<1, 128, 0, stream>>>(zsum, Whead, bhead, (float*)d_out, 1.0f / (float)N);

    // Z|R fused GEMM: A = [zx | phb], K=512, Ncols=512
    mm_bf16_k<<<dim3(nb, 4), 256, 0, stream>>>(zx, phb, 256, 256, 256, BtZR, 512, N,
                                               bZR, prev_h, nullptr, bufZ, buf1, EPI_ZR);
    // h GEMM: A = [zx | q], K=512, Ncols=256
    mm_bf16_k<<<dim3(nb, 2), 256, 0, stream>>>(zx, buf1, 256, 256, 256, BtH, 512, N,
                                               bH, prev_h, bufZ, hout, nullptr, EPI_H);
}

// Round 4
// 630.108 us; speedup vs baseline: 3.2840x; 1.0810x over previous
//
#include <hip/hip_runtime.h>
#include <math.h>

typedef __attribute__((ext_vector_type(8))) short short8;   // 8 bf16 = 4 VGPR
typedef __attribute__((ext_vector_type(4))) float f32x4;

__device__ inline unsigned short f2bf(float f) {
    unsigned int u = __float_as_uint(f);
    u += 0x7fffu + ((u >> 16) & 1u);          // RNE
    return (unsigned short)(u >> 16);
}
__device__ inline float bf2f(unsigned int h) { return __uint_as_float(h << 16); }

#define GLOAD_LDS16(gp, lp)                                                              \
    __builtin_amdgcn_global_load_lds(                                                    \
        (const __attribute__((address_space(1))) unsigned int*)(const void*)(gp),        \
        (__attribute__((address_space(3))) unsigned int*)(void*)(lp), 16, 0, 0)

// ---------------- degree / CSR ----------------

__global__ void init_k(float* deg, int* cnt, int N) {
    int i = blockIdx.x * blockDim.x + threadIdx.x;
    if (i < N) { deg[i] = 1.0f; cnt[i] = 0; }
}

__global__ void deg_cnt_k(const int* __restrict__ dst, const float* __restrict__ w,
                          float* deg, int* cnt, int E) {
    int e = blockIdx.x * blockDim.x + threadIdx.x;
    if (e < E) { int d = dst[e]; atomicAdd(&deg[d], w[e]); atomicAdd(&cnt[d], 1); }
}

__global__ void dinv_k(float* deg, int N) {
    int i = blockIdx.x * blockDim.x + threadIdx.x;
    if (i < N) { float d = deg[i]; deg[i] = d > 0.f ? rsqrtf(d) : 0.f; }
}

__global__ void scan_k(const int* __restrict__ cnt, int* __restrict__ rp,
                       int* __restrict__ ofs, int N) {
    __shared__ int buf[2][1024];
    __shared__ int carry_s;
    int tid = threadIdx.x;
    if (tid == 0) { carry_s = 0; rp[0] = 0; }
    __syncthreads();
    for (int base = 0; base < N; base += 1024) {
        int i = base + tid;
        int v = (i < N) ? cnt[i] : 0;
        int pp = 0;
        buf[0][tid] = v;
        __syncthreads();
        for (int o = 1; o < 1024; o <<= 1) {
            int nv = buf[pp][tid];
            if (tid >= o) nv += buf[pp][tid - o];
            buf[pp ^ 1][tid] = nv;
            pp ^= 1;
            __syncthreads();
        }
        int inc = buf[pp][tid];
        int c = carry_s;
        if (i < N) { rp[i + 1] = c + inc; ofs[i] = c + inc - v; }
        __syncthreads();
        if (tid == 1023) carry_s = c + inc;
        __syncthreads();
    }
}

__global__ void fill_csr_k(const int* __restrict__ src, const int* __restrict__ dst,
                           const float* __restrict__ w, const float* __restrict__ dinv,
                           int* ofs, int* __restrict__ csr_src, float* __restrict__ csr_norm, int E) {
    int e = blockIdx.x * blockDim.x + threadIdx.x;
    if (e < E) {
        int s = src[e], d = dst[e];
        int p = atomicAdd(&ofs[d], 1);
        csr_src[p] = s;
        csr_norm[p] = dinv[s] * w[e] * dinv[d];
    }
}

// ---------------- conversions ----------------

__global__ void cvt_x_k(const float* __restrict__ x, unsigned short* __restrict__ zx, int N) {
    int t = blockIdx.x * blockDim.x + threadIdx.x;
    if (t >= N * 32) return;
    int r = t >> 5, c4 = (t & 31) * 4;
    float4 v = *(const float4*)&x[(size_t)r * 128 + c4];
    uint2 o;
    o.x = (unsigned)f2bf(v.x) | ((unsigned)f2bf(v.y) << 16);
    o.y = (unsigned)f2bf(v.z) | ((unsigned)f2bf(v.w) << 16);
    *(uint2*)&zx[(size_t)r * 256 + 128 + c4] = o;
}

__global__ void cvt_ph_k(const float* __restrict__ ph, unsigned short* __restrict__ d, int N) {
    int t = blockIdx.x * blockDim.x + threadIdx.x;
    if (t >= N * 64) return;
    int r = t >> 6, c4 = (t & 63) * 4;
    float4 v = *(const float4*)&ph[(size_t)r * 256 + c4];
    uint2 o;
    o.x = (unsigned)f2bf(v.x) | ((unsigned)f2bf(v.y) << 16);
    o.y = (unsigned)f2bf(v.z) | ((unsigned)f2bf(v.w) << 16);
    *(uint2*)&d[(size_t)r * 256 + c4] = o;
}

// all weights -> bf16, transposed to Bt[n][k]
__global__ void cvtw_k(const float* W1, const float* W2,
                       const float* Wxz, const float* Whz, const float* Wxr, const float* Whr,
                       const float* Wxh, const float* Whh,
                       unsigned short* Bt1, unsigned short* Bt2,
                       unsigned short* BtZR, unsigned short* BtH) {
    int t = blockIdx.x * blockDim.x + threadIdx.x;
    if (t < 32768) { int k = t >> 8, n = t & 255; Bt1[(size_t)n * 128 + k] = f2bf(W1[t]); return; }
    t -= 32768;
    if (t < 32768) { int k = t >> 7, n = t & 127; Bt2[(size_t)n * 256 + k] = f2bf(W2[t]); return; }
    t -= 32768;
    if (t < 65536) { int k = t >> 8, n = t & 255; BtZR[(size_t)n * 512 + k] = f2bf(Wxz[t]); return; }
    t -= 65536;
    if (t < 65536) { int k = t >> 8, n = t & 255; BtZR[(size_t)n * 512 + 256 + k] = f2bf(Whz[t]); return; }
    t -= 65536;
    if (t < 65536) { int k = t >> 8, n = t & 255; BtZR[(size_t)(256 + n) * 512 + k] = f2bf(Wxr[t]); return; }
    t -= 65536;
    if (t < 65536) { int k = t >> 8, n = t & 255; BtZR[(size_t)(256 + n) * 512 + 256 + k] = f2bf(Whr[t]); return; }
    t -= 65536;
    if (t < 65536) { int k = t >> 8, n = t & 255; BtH[(size_t)n * 512 + k] = f2bf(Wxh[t]); return; }
    t -= 65536;
    if (t < 65536) { int k = t >> 8, n = t & 255; BtH[(size_t)n * 512 + 256 + k] = f2bf(Whh[t]); }
}

__global__ void bias_fuse_k(const float* bxz, const float* bhz, const float* bxr, const float* bhr,
                            const float* bxh, const float* bhh, float* bZR, float* bH) {
    int t = blockIdx.x * blockDim.x + threadIdx.x;
    if (t < 256)       bZR[t] = bxz[t] + bhz[t];
    else if (t < 512)  bZR[t] = bxr[t - 256] + bhr[t - 256];
    else if (t < 768)  bH[t - 512] = bxh[t - 512] + bhh[t - 512];
}

// ---------------- CSR gather (bf16 in, f32 accum, bf16 out) ----------------
template <int EPI>
__global__ void agg_bf_k(const int* __restrict__ rp, const int* __restrict__ cs,
                         const float* __restrict__ cn,
                         const unsigned short* __restrict__ X, int ldx2, int xo2,
                         const float* __restrict__ dinv, const float* __restrict__ bias,
                         unsigned short* __restrict__ Y, int ldy2, int yo2, int N) {
    int wid = (blockIdx.x * blockDim.x + threadIdx.x) >> 6;
    int lane = threadIdx.x & 63;
    if (wid >= N) return;
    const unsigned int* Xu = (const unsigned int*)X;
    float dv = dinv[wid]; dv *= dv;
    unsigned int sv = Xu[(size_t)wid * ldx2 + xo2 + lane];
    float ax = bf2f(sv & 0xffffu) * dv, ay = bf2f(sv >> 16) * dv;
    int p = rp[wid], pe = rp[wid + 1];
    for (; p + 4 <= pe; p += 4) {
        int s0 = cs[p], s1 = cs[p+1], s2 = cs[p+2], s3 = cs[p+3];
        float n0 = cn[p], n1 = cn[p+1], n2 = cn[p+2], n3 = cn[p+3];
        unsigned int v0 = Xu[(size_t)s0 * ldx2 + xo2 + lane];
        unsigned int v1 = Xu[(size_t)s1 * ldx2 + xo2 + lane];
        unsigned int v2 = Xu[(size_t)s2 * ldx2 + xo2 + lane];
        unsigned int v3 = Xu[(size_t)s3 * ldx2 + xo2 + lane];
        ax = fmaf(bf2f(v0 & 0xffffu), n0, ax); ay = fmaf(bf2f(v0 >> 16), n0, ay);
        ax = fmaf(bf2f(v1 & 0xffffu), n1, ax); ay = fmaf(bf2f(v1 >> 16), n1, ay);
        ax = fmaf(bf2f(v2 & 0xffffu), n2, ax); ay = fmaf(bf2f(v2 >> 16), n2, ay);
        ax = fmaf(bf2f(v3 & 0xffffu), n3, ax); ay = fmaf(bf2f(v3 >> 16), n3, ay);
    }
    for (; p < pe; ++p) {
        int s = cs[p]; float nv = cn[p];
        unsigned int v = Xu[(size_t)s * ldx2 + xo2 + lane];
        ax = fmaf(bf2f(v & 0xffffu), nv, ax); ay = fmaf(bf2f(v >> 16), nv, ay);
    }
    if (EPI == 1) {
        ax = fmaxf(ax + bias[lane * 2], 0.f);
        ay = fmaxf(ay + bias[lane * 2 + 1], 0.f);
    }
    unsigned int o = (unsigned)f2bf(ax) | ((unsigned)f2bf(ay) << 16);
    ((unsigned int*)Y)[(size_t)wid * ldy2 + yo2 + lane] = o;
}

// ---------------- head ----------------

__global__ void colsum_bf_k(const unsigned short* __restrict__ Z, float* zsum, int N) {
    int c = threadIdx.x;
    int rpb = (N + gridDim.x - 1) / gridDim.x;
    int r0 = blockIdx.x * rpb, r1 = min(N, r0 + rpb);
    float s = 0.f;
    for (int r = r0; r < r1; ++r) s += bf2f((unsigned int)Z[(size_t)r * 256 + c]);
    atomicAdd(&zsum[c], s);
}

__global__ void head_k(const float* __restrict__ zsum, const float* __restrict__ Wh,
                       const float* __restrict__ bh, float* __restrict__ out, float invN) {
    __shared__ float red[128];
    int c = threadIdx.x;
    red[c] = zsum[c] * invN * Wh[c];
    __syncthreads();
    for (int s = 64; s > 0; s >>= 1) {
        if (c < s) red[c] += red[c + s];
        __syncthreads();
    }
    if (c == 0) out[0] = red[0] + bh[0];
}

// ---------------- bf16 MFMA GEMM, 128x128 tile, global_load_lds staging ----------------
// C = concatK(A0|A1) @ Bt^T ; Bt is [Ncols][K] bf16. Linear LDS [row][32k].
// 1-D grid with XCD-bijective swizzle; decode (brow, bcol) with bcol fast.

enum { EPI_G = 0, EPI_P = 1, EPI_ZR = 2, EPI_H = 3 };

__global__ __launch_bounds__(256)
void mm_bf16_k(const unsigned short* __restrict__ A0, const unsigned short* __restrict__ A1,
               int lda0, int lda1, int kb,
               const unsigned short* __restrict__ Bt, int K, int M, int ncb,
               const float* __restrict__ bias,
               const unsigned short* __restrict__ xb1, const unsigned short* __restrict__ xb2,
               void* __restrict__ out, void* __restrict__ out2, int epi)
{
    __shared__ unsigned short Als[4096];   // 128 rows x 32 k
    __shared__ unsigned short Bls[4096];

    // XCD-bijective swizzle (m204), bcol fast -> A-panel reuse within an XCD's L2
    int nwg = gridDim.x;
    int bid = blockIdx.x;
    int q = nwg >> 3, r = nwg & 7;
    int xcd = bid & 7;
    int wg = (xcd < r ? xcd * (q + 1) : r * (q + 1) + (xcd - r) * q) + (bid >> 3);
    int brow = wg / ncb, bcol = wg - brow * ncb;
    int row0 = brow * 128, col0 = bcol * 128;

    int t = threadIdx.x;
    int w = t >> 6, lane = t & 63;
    int wr = w >> 1, wc = w & 1;
    int m15 = lane & 15, g = lane >> 4;

    int srow = lane >> 2;            // row within 16-row chunk
    int skk  = (lane & 3) * 8;       // k element offset

    f32x4 acc[4][4];
    #pragma unroll
    for (int i = 0; i < 4; ++i)
        #pragma unroll
        for (int j = 0; j < 4; ++j)
            #pragma unroll
            for (int qq = 0; qq < 4; ++qq) acc[i][j][qq] = 0.f;

    for (int kt = 0; kt < K; kt += 32) {
        const unsigned short* Ap = A0; int lda = lda0; int ka = kt;
        if (kt >= kb) { Ap = A1; lda = lda1; ka = kt - kb; }
        #pragma unroll
        for (int i = 0; i < 2; ++i) {
            int chunk = i * 4 + w;           // 0..7, per-wave uniform
            int arow = chunk * 16 + srow;
            int gr = row0 + arow; gr = gr < M ? gr : M - 1;
            GLOAD_LDS16(&Ap[(size_t)gr * lda + ka + skk], &Als[chunk * 512]);
            GLOAD_LDS16(&Bt[(size_t)(col0 + arow) * K + kt + skk], &Bls[chunk * 512]);
        }
        __syncthreads();                      // drains vmcnt before ds_read
        short8 af[4], bfr[4];
        #pragma unroll
        for (int ms = 0; ms < 4; ++ms) {
            int rt = wr * 64 + ms * 16 + m15;
            af[ms] = *(const short8*)&Als[rt * 32 + g * 8];
        }
        #pragma unroll
        for (int ns = 0; ns < 4; ++ns) {
            int nt = wc * 64 + ns * 16 + m15;
            bfr[ns] = *(const short8*)&Bls[nt * 32 + g * 8];
        }
        #pragma unroll
        for (int ms = 0; ms < 4; ++ms)
            #pragma unroll
            for (int ns = 0; ns < 4; ++ns)
                acc[ms][ns] = __builtin_amdgcn_mfma_f32_16x16x32_bf16(af[ms], bfr[ns], acc[ms][ns], 0, 0, 0);
        __syncthreads();                      // protect LDS before next stage
    }

    // epilogue: row = row0 + wr*64 + ms*16 + (lane>>4)*4 + i; col = col0 + wc*64 + ns*16 + m15
    int r4 = (lane >> 4) * 4;
    #pragma unroll
    for (int ms = 0; ms < 4; ++ms) {
        #pragma unroll
        for (int ns = 0; ns < 4; ++ns) {
            int col = col0 + wc * 64 + ns * 16 + m15;
            #pragma unroll
            for (int i = 0; i < 4; ++i) {
                int row = row0 + wr * 64 + ms * 16 + r4 + i;
                if (row >= M) continue;
                float v = acc[ms][ns][i];
                if (epi == EPI_G) {
                    float val = fmaxf(v + bias[col], 0.f) + bf2f((unsigned)xb1[(size_t)row * 256 + col]);
                    ((unsigned short*)out)[(size_t)row * 256 + col] = f2bf(val);
                } else if (epi == EPI_P) {
                    ((unsigned short*)out)[(size_t)row * 128 + col] = f2bf(v);
                } else if (epi == EPI_ZR) {
                    float s = 1.f / (1.f + __expf(-(v + bias[col])));
                    if (col < 256) {
                        ((unsigned short*)out)[(size_t)row * 256 + col] = f2bf(s);   // Z bf16
                    } else {
                        int c2 = col - 256;
                        ((unsigned short*)out2)[(size_t)row * 256 + c2] =
                            f2bf(bf2f((unsigned)xb1[(size_t)row * 256 + c2]) * s);   // q = ph*R
                    }
                } else {  // EPI_H
                    float s = v + bias[col];
                    float e = __expf(2.f * s);
                    float ht = 1.f - 2.f / (e + 1.f);
                    float Zt = bf2f((unsigned)xb2[(size_t)row * 256 + col]);
                    float ph = bf2f((unsigned)xb1[(size_t)row * 256 + col]);
                    ((float*)out)[(size_t)row * 256 + col] = Zt * ph + (1.f - Zt) * ht;
                }
            }
        }
    }
}

// ---------------- launch ----------------

extern "C" void kernel_launch(void* const* d_in, const int* in_sizes, int n_in,
                              void* d_out, int out_size, void* d_ws, size_t ws_size,
                              hipStream_t stream) {
    const float* x      = (const float*)d_in[0];
    const int*   ei     = (const int*)d_in[1];
    const float* ew     = (const float*)d_in[2];
    const float* prev_h = (const float*)d_in[3];
    const float* W1  = (const float*)d_in[4];  const float* b1  = (const float*)d_in[5];
    const float* W2  = (const float*)d_in[6];  const float* b2  = (const float*)d_in[7];
    const float* Wxz = (const float*)d_in[8];  const float* bxz = (const float*)d_in[9];
    const float* Whz = (const float*)d_in[10]; const float* bhz = (const float*)d_in[11];
    const float* Wxr = (const float*)d_in[12]; const float* bxr = (const float*)d_in[13];
    const float* Whr = (const float*)d_in[14]; const float* bhr = (const float*)d_in[15];
    const float* Wxh = (const float*)d_in[16]; const float* bxh = (const float*)d_in[17];
    const float* Whh = (const float*)d_in[18]; const float* bhh = (const float*)d_in[19];
    const float* Whead = (const float*)d_in[20]; const float* bhead = (const float*)d_in[21];

    const int N = in_sizes[0] / 128;
    const int E = in_sizes[2];
    const int* esrc = ei;
    const int* edst = ei + E;

    float* ws = (float*)d_ws;
    size_t o = 0;
    float* dinv     = ws + o; o += (size_t)N;
    int*   cnt      = (int*)(ws + o); o += (size_t)N;
    int*   rowp     = (int*)(ws + o); o += (size_t)N + 4;
    int*   csr_src  = (int*)(ws + o); o += (size_t)E;
    float* csr_norm = ws + o; o += (size_t)E;
    unsigned short* zx   = (unsigned short*)(ws + o); o += (size_t)N * 128;  // [N,256]: z | x
    unsigned short* phb  = (unsigned short*)(ws + o); o += (size_t)N * 128;  // prev_h bf16
    unsigned short* buf1 = (unsigned short*)(ws + o); o += (size_t)N * 128;  // t -> gw2 -> q
    unsigned short* Zbf  = (unsigned short*)(ws + o); o += (size_t)N * 128;  // g_bf -> Z bf16
    unsigned short* Bt1  = (unsigned short*)(ws + o); o += 16384;
    unsigned short* Bt2  = (unsigned short*)(ws + o); o += 16384;
    unsigned short* BtZR = (unsigned short*)(ws + o); o += 131072;
    unsigned short* BtH  = (unsigned short*)(ws + o); o += 65536;
    float* bZR      = ws + o; o += 512;
    float* bH       = ws + o; o += 256;
    float* zsum     = ws + o; o += 128;

    unsigned short* g_bf = Zbf;                     // [N,256] bf16, dead before Z written
    float* hout = (float*)d_out + 1;                // output 1: h [N,256]

    const int TPB = 256;
    int gN = (N + TPB - 1) / TPB;
    int gE = (E + TPB - 1) / TPB;
    int gAgg = (N * 64 + TPB - 1) / TPB;
    int nb = (N + 127) / 128;

    // norm + CSR
    init_k<<<gN, TPB, 0, stream>>>(dinv, cnt, N);
    deg_cnt_k<<<gE, TPB, 0, stream>>>(edst, ew, dinv, cnt, E);
    dinv_k<<<gN, TPB, 0, stream>>>(dinv, N);
    scan_k<<<1, 1024, 0, stream>>>(cnt, rowp, cnt, N);
    fill_csr_k<<<gE, TPB, 0, stream>>>(esrc, edst, ew, dinv, cnt, csr_src, csr_norm, E);

    // conversions
    cvt_x_k<<<(N * 32 + TPB - 1) / TPB, TPB, 0, stream>>>(x, zx, N);
    cvt_ph_k<<<(N * 64 + TPB - 1) / TPB, TPB, 0, stream>>>(prev_h, phb, N);
    cvtw_k<<<1792, TPB, 0, stream>>>(W1, W2, Wxz, Whz, Wxr, Whr, Wxh, Whh, Bt1, Bt2, BtZR, BtH);
    bias_fuse_k<<<3, TPB, 0, stream>>>(bxz, bhz, bxr, bhr, bxh, bhh, bZR, bH);

    // t = agg(x)
    agg_bf_k<0><<<gAgg, TPB, 0, stream>>>(rowp, csr_src, csr_norm, zx, 128, 64, dinv,
                                          nullptr, buf1, 64, 0, N);

    // g = relu(t@W1 + b1) + prev_h  -> g_bf [N,256]
    mm_bf16_k<<<nb * 2, 256, 0, stream>>>(buf1, buf1, 128, 128, 128, Bt1, 128, N, 2,
                                          b1, phb, nullptr, g_bf, nullptr, EPI_G);
    // gw2 = g@W2 -> buf1 [N,128]
    mm_bf16_k<<<nb, 256, 0, stream>>>(g_bf, g_bf, 256, 256, 256, Bt2, 256, N, 1,
                                      nullptr, nullptr, nullptr, buf1, nullptr, EPI_P);
    // z = relu(agg(gw2) + b2) -> zx cols 0..127
    agg_bf_k<1><<<gAgg, TPB, 0, stream>>>(rowp, csr_src, csr_norm, buf1, 64, 0, dinv,
                                          b2, zx, 128, 0, N);

    // head
    hipMemsetAsync(zsum, 0, 128 * sizeof(float), stream);
    colsum_bf_k<<<512, 128, 0, stream>>>(zx, zsum, N);
    head_k<<<1, 128, 0, stream>>>(zsum, Whead, bhead, (float*)d_out, 1.0f / (float)N);

    // Z|R fused GEMM: A = [zx | phb], K=512, Ncols=512 -> Z (bf16) + q
    mm_bf16_k<<<nb * 4, 256, 0, stream>>>(zx, phb, 256, 256, 256, BtZR, 512, N, 4,
                                          bZR, phb, nullptr, Zbf, buf1, EPI_ZR);
    // h GEMM: A = [zx | q], K=512, Ncols=256 -> h (f32, d_out+1)
    mm_bf16_k<<<nb * 2, 256, 0, stream>>>(zx, buf1, 256, 256, 256, BtH, 512, N, 2,
                                          bH, phb, Zbf, hout, nullptr, EPI_H);
}